// Round 10
// baseline (531.000 us; speedup 1.0000x reference)
//
#include <hip/hip_runtime.h>
#include <hip/hip_bf16.h>

typedef __hip_bfloat16 bf16;

#define N_NODES 100000
#define N_EDGES 1600000
#define D_IN    100
#define D_HID   50
#define N_REL   237
#define N_REL2  474
#define N_CLASS 50

// Canonical fp32 weight-block offsets (element offsets into wc)
#define O_RELEMB 0
#define O_RELW   23700
#define O_BASIS1 28700
#define O_COMP1  53700
#define O_ROOT1  56070
#define O_BIAS1  61070
#define O_BASIS2 61120
#define O_COMP2  73620
#define O_ROOT2  75990
#define O_BIAS2  78490
#define W_TOTAL  78540

// binned scatter
#define NBUCK    128
#define BSHIFT   10
#define BCAP     20480
#define BIN_EPB  1024
#define BIN_BLKS ((N_EDGES + BIN_EPB - 1) / BIN_EPB)   // 1563

// prep1 grid partition (256-thread blocks): convert_x | convert_w | bin
#define P1_CVTX_BLKS 50000
#define P1_CVTW_BLKS 307
#define P1_TOTAL (P1_CVTX_BLKS + P1_CVTW_BLKS + BIN_BLKS)

// prep2 grid partition: pack1 | pack2 | rel(+sentinel row)
#define P2_PACK1_BLKS 160
#define P2_PACK2_BLKS 80
#define P2_REL_BLKS   475             // 474 relations + 1 zero sentinel row
#define P2_TOTAL (P2_PACK1_BLKS + P2_PACK2_BLKS + P2_REL_BLKS)

#define T_SENT   474u                 // sentinel relation id (zero weights)

typedef __attribute__((ext_vector_type(8))) short short8;
typedef __attribute__((ext_vector_type(4))) float f32x4;
typedef __attribute__((ext_vector_type(2))) float f32x2;

__device__ __forceinline__ float b2f(bf16 v) { return __bfloat162float(v); }
__device__ __forceinline__ bf16  f2b(float v) { return __float2bfloat16(v); }
__device__ __forceinline__ unsigned f2b_bits(float v) {
    bf16 b = f2b(v);
    unsigned short u;
    __builtin_memcpy(&u, &b, 2);
    return (unsigned)u;
}

#if __has_builtin(__builtin_amdgcn_cvt_f32_fp8) && __has_builtin(__builtin_amdgcn_cvt_pk_fp8_f32)
#define F8_HW 1
#endif
#if __has_builtin(__builtin_amdgcn_cvt_pk_f32_fp8)
#define F8PK_HW 1
#endif

// ---- fp8 e4m3 (OCP, gfx950 HW) helpers ----
__device__ __forceinline__ float f8tof(unsigned u) {
#ifdef F8_HW
    return __builtin_amdgcn_cvt_f32_fp8((int)u, 0);
#else
    unsigned s = u >> 7, e = (u >> 3) & 0xF, m = u & 7;
    float v;
    if (e == 0) v = (float)m * 0.001953125f;
    else        v = (float)(8 + m) * __builtin_ldexpf(1.f, (int)e - 10);
    return s ? -v : v;
#endif
}

#ifdef F8_HW
#define F8SEL(u, s) __builtin_amdgcn_cvt_f32_fp8((int)(u), (s))
#else
#define F8SEL(u, s) f8tof(((u) >> (8 * (s))) & 0xFFu)
#endif

template <bool HI>
__device__ __forceinline__ f32x2 f8pk(unsigned u) {
#ifdef F8PK_HW
    return __builtin_amdgcn_cvt_pk_f32_fp8((int)u, HI);
#else
    f32x2 r;
    r.x = F8SEL(u, HI ? 2 : 0);
    r.y = F8SEL(u, HI ? 3 : 1);
    return r;
#endif
}

__device__ __forceinline__ unsigned f8enc_sw(float v) {
    unsigned bits = __float_as_uint(v);
    unsigned s = bits >> 31;
    float a = fabsf(v);
    if (a < 0.0009765625f) return s << 7;
    if (a >= 448.f) return (s << 7) | 0x7E;
    int E = (int)((bits >> 23) & 0xFF) - 127;
    unsigned m = bits & 0x7FFFFF;
    if (E < -6) {
        int q = (int)rintf(a * 512.f);
        if (q > 7) q = 7;
        return (s << 7) | (unsigned)q;
    }
    unsigned lsb = (m >> 20) & 1, rnd = (m >> 19) & 1;
    unsigned sticky = (m & 0x7FFFF) ? 1u : 0u;
    unsigned m3 = (m >> 20) + (rnd & (sticky | lsb));
    if (m3 == 8) { m3 = 0; E += 1; }
    if (E > 8) return (s << 7) | 0x7E;
    return (s << 7) | ((unsigned)(E + 7) << 3) | m3;
}

__device__ __forceinline__ unsigned pk4_f8(float v0, float v1, float v2, float v3) {
#ifdef F8_HW
    int p = __builtin_amdgcn_cvt_pk_fp8_f32(v0, v1, 0, false);
    p = __builtin_amdgcn_cvt_pk_fp8_f32(v2, v3, p, true);
    return (unsigned)p;
#else
    return f8enc_sw(v0) | (f8enc_sw(v1) << 8) | (f8enc_sw(v2) << 16) | (f8enc_sw(v3) << 24);
#endif
}

// ---- dtype detection: flag[0]=1 if float arrays are stored as bf16, 0 if fp32.
__global__ void k_detect(const unsigned short* __restrict__ xr, int* __restrict__ flag) {
    int tid = threadIdx.x;
    int cnt = 0;
    for (int i = tid; i < 4096; i += 256) {
        unsigned short u = xr[2 * i];
        unsigned e = (u >> 7) & 0xFF;
        bool pl = (e >= 107 && e <= 132) || ((u & 0x7FFF) == 0);
        cnt += pl ? 1 : 0;
    }
    __shared__ int sh[256];
    sh[tid] = cnt;
    __syncthreads();
    for (int s = 128; s > 0; s >>= 1) {
        if (tid < s) sh[tid] += sh[tid + s];
        __syncthreads();
    }
    if (tid == 0) flag[0] = (sh[0] >= 3072) ? 1 : 0;
}

struct WPtrs { const void* p[10]; };

// ---- bin job: per-block LDS counting-sort of 1024 edges into bucket staging
__device__ __forceinline__ void job_bin(int blk, const int* __restrict__ src,
                                        const int* __restrict__ dst,
                                        const int* __restrict__ et,
                                        unsigned* __restrict__ bucketFill,
                                        unsigned long long* __restrict__ staging) {
    __shared__ unsigned lhist[NBUCK];
    __shared__ unsigned lstart[NBUCK];
    __shared__ unsigned gbase[NBUCK];
    __shared__ unsigned scan_tmp[NBUCK];
    __shared__ unsigned long long lval[BIN_EPB];
    __shared__ unsigned ltgt[BIN_EPB];
    int tid = threadIdx.x;
    int base = blk * BIN_EPB;
    int n = N_EDGES - base; if (n > BIN_EPB) n = BIN_EPB;

    for (int i = tid; i < NBUCK; i += 256) lhist[i] = 0;
    __syncthreads();

    unsigned bb[4], rr[4];
    unsigned long long vv[4];
#pragma unroll
    for (int j = 0; j < 4; ++j) {
        int i = j * 256 + tid;
        bb[j] = 0xFFFFFFFFu;
        if (i < n) {
            int e = base + i;
            unsigned d = (unsigned)dst[e];
            unsigned b = d >> BSHIFT;
            bb[j] = b;
            rr[j] = atomicAdd(&lhist[b], 1u);
            vv[j] = ((unsigned long long)d << 32) |
                    (unsigned long long)((unsigned)src[e] | ((unsigned)et[e] << 17));
        }
    }
    __syncthreads();
    unsigned v0 = (tid < NBUCK) ? lhist[tid] : 0;
    if (tid < NBUCK) scan_tmp[tid] = v0;
    __syncthreads();
    for (int s = 1; s < NBUCK; s <<= 1) {
        unsigned t = 0;
        if (tid < NBUCK && tid >= (unsigned)s) t = scan_tmp[tid - s];
        __syncthreads();
        if (tid < NBUCK) scan_tmp[tid] += t;
        __syncthreads();
    }
    if (tid < NBUCK) {
        lstart[tid] = scan_tmp[tid] - v0;
        gbase[tid] = (v0 > 0) ? atomicAdd(&bucketFill[tid], v0) : 0u;
    }
    __syncthreads();
#pragma unroll
    for (int j = 0; j < 4; ++j) {
        if (bb[j] != 0xFFFFFFFFu) {
            unsigned pos = lstart[bb[j]] + rr[j];
            unsigned off = gbase[bb[j]] + rr[j];
            lval[pos] = vv[j];
            ltgt[pos] = (off < BCAP) ? (bb[j] * BCAP + off) : 0xFFFFFFFFu;
        }
    }
    __syncthreads();
    for (int i = tid; i < n; i += 256) {
        unsigned t = ltgt[i];
        if (t != 0xFFFFFFFFu) staging[t] = lval[i];
    }
}

// ================= fused prep1: convert_x | convert_w | bin ==================
__global__ __launch_bounds__(256) void k_prep1(const void* __restrict__ xr,
                                               const int* __restrict__ flag,
                                               bf16* __restrict__ xc,
                                               WPtrs wp, float* __restrict__ wc,
                                               const int* __restrict__ srcp,
                                               const int* __restrict__ dstp,
                                               const int* __restrict__ etp,
                                               unsigned* __restrict__ bucketFill,
                                               unsigned long long* __restrict__ staging) {
    int blk = blockIdx.x;
    if (blk < P1_CVTX_BLKS) {
        int g = blk * 256 + threadIdx.x;
        int row = g >> 7, col = g & 127;
        bf16 o = f2b(0.f);
        if (col < D_IN) {
            if (flag[0]) o = ((const bf16*)xr)[row * D_IN + col];
            else         o = f2b(((const float*)xr)[row * D_IN + col]);
        }
        xc[g] = o;
        return;
    }
    blk -= P1_CVTX_BLKS;
    if (blk < P1_CVTW_BLKS) {
        const int sz[10] = {23700, 5000, 25000, 2370, 5000, 50, 12500, 2370, 2500, 50};
        int g = blk * 256 + threadIdx.x;
        if (g >= W_TOTAL) return;
        int j = 0, base = 0;
        while (j < 9 && g >= base + sz[j]) { base += sz[j]; ++j; }
        int idx = g - base;
        float v;
        if (flag[0]) v = b2f(((const bf16*)wp.p[j])[idx]);
        else         v = ((const float*)wp.p[j])[idx];
        wc[g] = v;
        return;
    }
    blk -= P1_CVTW_BLKS;
    job_bin(blk, srcp, dstp, etp, bucketFill, staging);
}

// ================= per-bucket CSR build: offs + se, zero global atomics ======
__global__ __launch_bounds__(1024) void k_bucket(const unsigned long long* __restrict__ staging,
                                                 const unsigned* __restrict__ bucketFill,
                                                 int* __restrict__ offs,
                                                 unsigned* __restrict__ se) {
    __shared__ unsigned hist[1024];
    __shared__ unsigned excl[1024];
    __shared__ unsigned bfs[NBUCK];
    int tid = threadIdx.x;
    int b = blockIdx.x;

    if (tid < NBUCK) {
        unsigned c = bucketFill[tid];
        bfs[tid] = (c > BCAP) ? BCAP : c;
    }
    hist[tid] = 0;
    __syncthreads();
    for (int s = 1; s < NBUCK; s <<= 1) {
        unsigned t = 0;
        if (tid < NBUCK && tid >= (unsigned)s) t = bfs[tid - s];
        __syncthreads();
        if (tid < NBUCK) bfs[tid] += t;
        __syncthreads();
    }
    unsigned base = (b == 0) ? 0u : bfs[b - 1];
    unsigned cnt = bfs[b] - base;

    const unsigned long long* p = staging + (size_t)b * BCAP;
    for (unsigned i = tid; i < cnt; i += 1024) {
        unsigned d = (unsigned)(p[i] >> 32);
        atomicAdd(&hist[d & 1023], 1u);
    }
    __syncthreads();
    excl[tid] = hist[tid];
    __syncthreads();
    for (int s = 1; s < 1024; s <<= 1) {
        unsigned t = (tid >= s) ? excl[tid - s] : 0u;
        __syncthreads();
        excl[tid] += t;
        __syncthreads();
    }
    unsigned my_excl = excl[tid] - hist[tid];
    __syncthreads();
    excl[tid] = my_excl;
    hist[tid] = 0;
    __syncthreads();

    int node = b * 1024 + tid;
    if (node < N_NODES) offs[node] = (int)(base + my_excl);
    if (node == N_NODES - 1) offs[N_NODES] = (int)(base + cnt);

    for (unsigned i = tid; i < cnt; i += 1024) {
        unsigned long long v = p[i];
        unsigned ld = ((unsigned)(v >> 32)) & 1023u;
        unsigned r = atomicAdd(&hist[ld], 1u);
        se[base + excl[ld] + r] = (unsigned)v;
    }
}

// ---- pack job body: basis[5][KL][50] + root[KL][50] -> MFMA B-fragment order
__device__ __forceinline__ void job_pack(int blk, const float* basis, const float* root,
                                         bf16* Wb, int KL) {
    int g = blk * 256 + threadIdx.x;
    int ks = g / 10240;
    int r = g - ks * 10240;
    int ct = r >> 9;
    int r2 = r & 511;
    int l = r2 >> 3, j = r2 & 7;
    int k = ks * 32 + ((l >> 4) << 3) + j;
    int n = ct * 16 + (l & 15);
    float v = 0.f;
    if (k < KL && n < 300) {
        if (n < 250) { int b = n / 50, f = n - b * 50; v = basis[(b * KL + k) * 50 + f]; }
        else         v = root[k * 50 + (n - 250)];
    }
    Wb[g] = f2b(v);
}

// ================= fused prep2: pack1 | pack2 | rel (+ zero sentinel) ========
__global__ __launch_bounds__(256) void k_prep2(const float* __restrict__ wc,
                                               bf16* __restrict__ Wb1, bf16* __restrict__ Wb2,
                                               float* __restrict__ rt1, float* __restrict__ rt2,
                                               float* __restrict__ c81, float* __restrict__ c82) {
    int blk = blockIdx.x;
    if (blk < P2_PACK1_BLKS) { job_pack(blk, wc + O_BASIS1, wc + O_ROOT1, Wb1, D_IN); return; }
    blk -= P2_PACK1_BLKS;
    if (blk < P2_PACK2_BLKS) { job_pack(blk, wc + O_BASIS2, wc + O_ROOT2, Wb2, D_HID); return; }
    blk -= P2_PACK2_BLKS;
    {
        int t = blk;
        int tid = threadIdx.x;
        if (t == (int)T_SENT) {      // zero sentinel row for the reduce odd-tail
            if (tid < 50) { rt1[t * 50 + tid] = 0.f; rt2[t * 50 + tid] = 0.f; }
            if (tid < 8)  { c81[t * 8 + tid] = 0.f;  c82[t * 8 + tid] = 0.f; }
            return;
        }
        const float* rel_emb = wc + O_RELEMB;
        const float* rel_w   = wc + O_RELW;
        const float* basis1  = wc + O_BASIS1;
        const float* comp1   = wc + O_COMP1;
        const float* basis2  = wc + O_BASIS2;
        const float* comp2   = wc + O_COMP2;
        __shared__ float rf[D_IN];
        __shared__ float r2s[D_HID];
        int tm = (t >= N_REL) ? t - N_REL : t;
        if (tid < D_IN) rf[tid] = rel_emb[tm * D_IN + tid];
        if (tid < 8) {
            c81[t * 8 + tid] = (tid < 5) ? comp1[t * 5 + tid] : 0.f;
            c82[t * 8 + tid] = (tid < 5) ? comp2[t * 5 + tid] : 0.f;
        }
        __syncthreads();
        if (tid < 50) {
            int f = tid;
            float a = 0.f;
            for (int b = 0; b < 5; ++b) {
                float cb = comp1[t * 5 + b];
                float s = 0.f;
                for (int k = 0; k < D_IN; ++k) s += rf[k] * basis1[(b * D_IN + k) * 50 + f];
                a += cb * s;
            }
            rt1[t * 50 + f] = a;
            float s2 = 0.f;
            for (int k = 0; k < D_IN; ++k) s2 += rf[k] * rel_w[k * 50 + f];
            r2s[f] = s2;
        }
        __syncthreads();
        if (tid < 50) {
            int f = tid;
            float a = 0.f;
            for (int b = 0; b < 5; ++b) {
                float cb = comp2[t * 5 + b];
                float s = 0.f;
                for (int k = 0; k < 50; ++k) s += r2s[k] * basis2[(b * 50 + k) * 50 + f];
                a += cb * s;
            }
            rt2[t * 50 + f] = a;
        }
    }
}

// ---- MFMA GEMM: [X @ Wb] -> Y8 (fp8, plane-split 256 B rows) + R (bf16 root)
template<int KP, bool ZT>
__global__ __launch_bounds__(256) void k_gemm_mfma(const bf16* __restrict__ X,
                                                   const bf16* __restrict__ Wb,
                                                   unsigned char* __restrict__ Y8,
                                                   bf16* __restrict__ R, int M,
                                                   const int* __restrict__ tgt) {
    __shared__ bf16 smem[64 * 320];   // 40 KB
    int tid = threadIdx.x;
    int w = tid >> 6, lane = tid & 63;
    int quad = lane >> 4, cIn = lane & 15;
    int base_row = blockIdx.x * 64;

    const int TOT = 64 * KP / 8;
    for (int i = tid; i < TOT; i += 256) {
        int e8 = i * 8;
        int r = e8 / KP, c = e8 - r * KP;
        int row = base_row + r; if (row > M - 1) row = M - 1;
        *(uint4*)(&smem[r * KP + c]) = *(const uint4*)(&X[(size_t)row * KP + c]);
    }
    __syncthreads();

    f32x4 acc[20];
#pragma unroll
    for (int i = 0; i < 20; ++i) acc[i] = (f32x4){0.f, 0.f, 0.f, 0.f};

#pragma unroll
    for (int ks = 0; ks < KP / 32; ++ks) {
        short8 a = *(const short8*)(&smem[(w * 16 + cIn) * KP + ks * 32 + quad * 8]);
#pragma unroll
        for (int ct = 0; ct < 20; ++ct) {
            short8 b = *(const short8*)(&Wb[(size_t)((ks * 20 + ct) * 64 + lane) * 8]);
            acc[ct] = __builtin_amdgcn_mfma_f32_16x16x32_bf16(a, b, acc[ct], 0, 0, 0);
        }
    }
    __syncthreads();

#pragma unroll
    for (int ct = 0; ct < 20; ++ct)
#pragma unroll
        for (int r = 0; r < 4; ++r)
            smem[(w * 16 + quad * 4 + r) * 320 + ct * 16 + cIn] = f2b(acc[ct][r]);
    __syncthreads();

    int tv = -1;
    if (ZT) tv = tgt[0];
    int valid = M - base_row; if (valid > 64) valid = 64;

    for (int i = tid; i < valid * 64; i += 256) {
        int r = i >> 6, u = i & 63;
        int row = base_row + r;
        unsigned pbits;
        if (u < 50) {
            pbits = pk4_f8(b2f(smem[r * 320 + u]),       b2f(smem[r * 320 + 50 + u]),
                           b2f(smem[r * 320 + 100 + u]), b2f(smem[r * 320 + 150 + u]));
        } else if (u < 63) {
            int fb = (u - 50) * 4;
            float v0 = (fb + 0 < 50) ? b2f(smem[r * 320 + 200 + fb + 0]) : 0.f;
            float v1 = (fb + 1 < 50) ? b2f(smem[r * 320 + 200 + fb + 1]) : 0.f;
            float v2 = (fb + 2 < 50) ? b2f(smem[r * 320 + 200 + fb + 2]) : 0.f;
            float v3 = (fb + 3 < 50) ? b2f(smem[r * 320 + 200 + fb + 3]) : 0.f;
            pbits = pk4_f8(v0, v1, v2, v3);
        } else {
            pbits = 0u;
        }
        if (ZT && row == tv) pbits = 0u;
        *(unsigned*)(Y8 + (size_t)row * 256 + u * 4) = pbits;
    }
    for (int i = tid; i < valid * 32; i += 256) {
        int r = i >> 5, cu = i & 31;
        int row = base_row + r;
        int j0 = cu * 2, j1 = j0 + 1;
        unsigned short ua = (j0 < 50) ? *(const unsigned short*)&smem[r * 320 + 250 + j0] : 0;
        unsigned short ub = (j1 < 50) ? *(const unsigned short*)&smem[r * 320 + 250 + j1] : 0;
        unsigned u = (unsigned)ua | ((unsigned)ub << 16);
        if (ZT && row == tv) u = 0u;
        *(unsigned*)((unsigned short*)R + (size_t)row * 64 + j0) = u;
    }
}

// ================= half-wave edge-pair gather-reduce =========================
// Wave = 1 node row; lanes 0-31 handle edge e, lanes 32-63 edge e+1.
// Lane j (0..31, jj=min(j,24)) covers column pair (2jj, 2jj+1).
// Odd tail handled branch-free via sentinel relation T_SENT (zero c8/rt rows).
#define PAIR_LOOP                                                             \
    f32x2 acc; acc.x = 0.f; acc.y = 0.f;                                      \
    _Pragma("unroll 2")                                                       \
    for (int e = e0; e < e1; e += 2) {                                        \
        int idx = e + half;                                                   \
        unsigned p = (idx < e1) ? se[idx] : (T_SENT << 17);                   \
        int s_ = (int)(p & 0x1FFFFu);                                         \
        int t_ = (int)(p >> 17);                                              \
        const unsigned char* yr = Y8 + (size_t)s_ * 256;                      \
        uint2 a8 = *(const uint2*)(yr + offA);                                \
        unsigned bw = *(const unsigned short*)(yr + offB);                    \
        const float* cp_ = c8 + t_ * 8;                                       \
        f32x4 c03 = *(const f32x4*)cp_;                                       \
        float c4 = cp_[4];                                                    \
        f32x2 rv = *(const f32x2*)(rt + t_ * 50 + 2 * jj);                    \
        f32x2 ya0 = f8pk<false>(a8.x);                                        \
        f32x2 ya1 = f8pk<true>(a8.x);                                         \
        f32x2 yb0 = f8pk<false>(a8.y);                                        \
        f32x2 yb1 = f8pk<true>(a8.y);                                         \
        f32x2 y4 = f8pk<false>(bw);                                           \
        f32x2 ct2;                                                            \
        ct2.x = c03.x * ya0.x + c03.y * ya0.y + c03.z * ya1.x + c03.w * ya1.y;\
        ct2.y = c03.x * yb0.x + c03.y * yb0.y + c03.z * yb1.x + c03.w * yb1.y;\
        f32x2 c4v; c4v.x = c4; c4v.y = c4;                                    \
        ct2 += c4v * y4;                                                      \
        ct2 += rv;                                                            \
        acc += ct2;                                                           \
    }                                                                         \
    acc.x += __shfl_xor(acc.x, 32);                                           \
    acc.y += __shfl_xor(acc.y, 32);

// Layer 1: h[row][0..63] = mean_agg + x@root (R) + bias (cols>=50 zero)
__global__ __launch_bounds__(256) void k_reduce1(const int* __restrict__ off,
                                                 const unsigned int* __restrict__ se,
                                                 const float* __restrict__ c8,
                                                 const float* __restrict__ rt,
                                                 const unsigned char* __restrict__ Y8,
                                                 const bf16* __restrict__ R,
                                                 const float* __restrict__ bias_,
                                                 bf16* __restrict__ h) {
    int wid = threadIdx.x >> 6, lane = threadIdx.x & 63;
    int half = lane >> 5, j = lane & 31;
    int jj = (j < 25) ? j : 24;
    int offA = 8 * jj, offB = 200 + 2 * jj;
    int row = blockIdx.x * 4 + wid;
    if (row >= N_NODES) return;
    int e0 = off[row], e1 = off[row + 1];
    PAIR_LOOP
    float c = (float)(e1 - e0); c = c > 1.f ? c : 1.f;
    unsigned Ru = *(const unsigned*)((const unsigned short*)R + (size_t)row * 64 + 2 * jj);
    float r0 = __uint_as_float(Ru << 16);
    float r1 = __uint_as_float(Ru & 0xffff0000u);
    f32x2 bv = *(const f32x2*)(bias_ + 2 * jj);
    float v0 = acc.x / c + r0 + bv.x;
    float v1 = acc.y / c + r1 + bv.y;
    if (half == 0) {
        unsigned* hp = (unsigned*)((unsigned short*)h + (size_t)row * 64);
        hp[j] = (j < 25) ? (f2b_bits(v0) | (f2b_bits(v1) << 16)) : 0u;
    }
}

// Layer 2: same reduce + log_softmax epilogue; dual-dtype output store.
__global__ __launch_bounds__(256) void k_reduce2(const int* __restrict__ off,
                                                 const unsigned int* __restrict__ se,
                                                 const float* __restrict__ c8,
                                                 const float* __restrict__ rt,
                                                 const unsigned char* __restrict__ Y8,
                                                 const bf16* __restrict__ R,
                                                 const float* __restrict__ bias_,
                                                 const int* __restrict__ flag,
                                                 void* __restrict__ out) {
    int wid = threadIdx.x >> 6, lane = threadIdx.x & 63;
    int half = lane >> 5, j = lane & 31;
    int jj = (j < 25) ? j : 24;
    int offA = 8 * jj, offB = 200 + 2 * jj;
    int row = blockIdx.x * 4 + wid;
    if (row >= N_NODES) return;
    int e0 = off[row], e1 = off[row + 1];
    PAIR_LOOP
    float c = (float)(e1 - e0); c = c > 1.f ? c : 1.f;
    unsigned Ru = *(const unsigned*)((const unsigned short*)R + (size_t)row * 64 + 2 * jj);
    float r0 = __uint_as_float(Ru << 16);
    float r1 = __uint_as_float(Ru & 0xffff0000u);
    f32x2 bv = *(const f32x2*)(bias_ + 2 * jj);
    float v0 = acc.x / c + r0 + bv.x;
    float v1 = acc.y / c + r1 + bv.y;
    // softmax over 50 cols; both halves hold identical values -> mask sum to half 0
    float m = (j < 25) ? fmaxf(v0, v1) : -INFINITY;
    for (int o = 32; o > 0; o >>= 1) m = fmaxf(m, __shfl_xor(m, o));
    float ex = (half == 0 && j < 25) ? (expf(v0 - m) + expf(v1 - m)) : 0.f;
    float s = ex;
    for (int o = 32; o > 0; o >>= 1) s += __shfl_xor(s, o);
    float ls = logf(s);
    if (half == 0 && j < 25) {
        float o0 = v0 - m - ls, o1 = v1 - m - ls;
        if (flag[0]) {
            ((unsigned*)out)[(size_t)row * 25 + j] = f2b_bits(o0) | (f2b_bits(o1) << 16);
        } else {
            f32x2 ov; ov.x = o0; ov.y = o1;
            *(f32x2*)((float*)out + (size_t)row * 50 + 2 * j) = ov;
        }
    }
}

extern "C" void kernel_launch(void* const* d_in, const int* in_sizes, int n_in,
                              void* d_out, int out_size, void* d_ws, size_t ws_size,
                              hipStream_t stream) {
    const void* x_raw = d_in[0];
    const int*  ei    = (const int*)d_in[1];
    const int*  et    = (const int*)d_in[2];
    const int*  tgt   = (const int*)d_in[3];

    char* wsp = (char*)d_ws;
    size_t off_b = 0;
    auto alloc = [&](size_t bytes) {
        void* p = wsp + off_b;
        off_b = (off_b + bytes + 255) & ~(size_t)255;
        return p;
    };
    unsigned char* Y8 = (unsigned char*)alloc((size_t)N_NODES * 256);       // 25.6 MB
    bf16*  R    = (bf16*) alloc((size_t)N_NODES * 64 * sizeof(bf16));       // 12.8 MB
    bf16*  xc   = (bf16*) alloc((size_t)N_NODES * 128 * sizeof(bf16));      // 25.6 MB
    bf16*  h    = xc;   // alias: xc dead after layer-1 GEMM
    unsigned int* se = (unsigned int*)alloc((size_t)N_EDGES * sizeof(unsigned int)); // 6.4 MB
    unsigned long long* staging = (unsigned long long*)alloc((size_t)NBUCK * BCAP * 8); // 21 MB
    int*   offs = (int*)  alloc((size_t)(N_NODES + 1) * sizeof(int));
    unsigned* bucketFill = (unsigned*)alloc((size_t)NBUCK * sizeof(unsigned));
    float* wc   = (float*)alloc((size_t)W_TOTAL * sizeof(float));
    bf16*  Wb1  = (bf16*) alloc((size_t)40960 * sizeof(bf16));
    bf16*  Wb2  = (bf16*) alloc((size_t)20480 * sizeof(bf16));
    float* rt1  = (float*)alloc((size_t)475 * 50 * sizeof(float));   // +sentinel row
    float* rt2  = (float*)alloc((size_t)475 * 50 * sizeof(float));
    float* c81  = (float*)alloc((size_t)475 * 8 * sizeof(float));
    float* c82  = (float*)alloc((size_t)475 * 8 * sizeof(float));
    int*   flag = (int*)  alloc(sizeof(int));

    const int* srcp = ei;
    const int* dstp = ei + N_EDGES;

    hipMemsetAsync(bucketFill, 0, (size_t)NBUCK * sizeof(unsigned), stream);

    WPtrs wp;
    for (int i = 0; i < 10; ++i) wp.p[i] = d_in[4 + i];

    k_detect<<<1, 256, 0, stream>>>((const unsigned short*)x_raw, flag);
    k_prep1<<<P1_TOTAL, 256, 0, stream>>>(x_raw, flag, xc, wp, wc, srcp, dstp, et,
                                          bucketFill, staging);
    k_prep2<<<P2_TOTAL, 256, 0, stream>>>(wc, Wb1, Wb2, rt1, rt2, c81, c82);
    k_bucket<<<NBUCK, 1024, 0, stream>>>(staging, bucketFill, offs, se);

    // Layer 1
    k_gemm_mfma<128, true><<<(N_NODES + 63) / 64, 256, 0, stream>>>(xc, Wb1, Y8, R, N_NODES, tgt);
    k_reduce1<<<(N_NODES + 3) / 4, 256, 0, stream>>>(offs, se, c81, rt1, Y8, R, wc + O_BIAS1, h);

    // Layer 2
    k_gemm_mfma<64, false><<<(N_NODES + 63) / 64, 256, 0, stream>>>(h, Wb2, Y8, R, N_NODES, nullptr);
    k_reduce2<<<(N_NODES + 3) / 4, 256, 0, stream>>>(offs, se, c82, rt2, Y8, R, wc + O_BIAS2, flag, d_out);
}